// Round 10
// baseline (47.471 us; speedup 1.0000x reference)
//
#include <hip/hip_runtime.h>
#include <hip/hip_bf16.h>

#define B_SZ   1024
#define NIN    64
#define NOUT   4096
#define NBATCH 64
#define NCONT  16
#define KTOT   96      // z(64) | cont(16) | zero-pad(16)
#define PCAP   48      // per-batch sample capacity (Poisson(16) max ~32)

#define WT_ELEMS   (NOUT * KTOT)              // 393216
#define XT_ELEMS   (B_SZ * KTOT)              // 98304
#define WT_BLOCKS  (WT_ELEMS / 256)           // 1536
#define XT_BLOCKS  (XT_ELEMS / 256)           // 384

typedef __attribute__((ext_vector_type(8))) short short8;   // 8 bf16 = 4 VGPR
typedef __attribute__((ext_vector_type(4))) float f32x4;

// f32 -> bf16 bits, round-to-nearest-even
__device__ __forceinline__ short f2bf(float f) {
    unsigned u = __float_as_uint(f);
    return (short)((u + 0x7FFFu + ((u >> 16) & 1u)) >> 16);
}

__device__ __forceinline__ short8 mkbf(float4 wa, float4 wb, float4 ea, float4 eb) {
    short8 r;
    r[0]=f2bf(wa.x+ea.x); r[1]=f2bf(wa.y+ea.y); r[2]=f2bf(wa.z+ea.z); r[3]=f2bf(wa.w+ea.w);
    r[4]=f2bf(wb.x+eb.x); r[5]=f2bf(wb.y+eb.y); r[6]=f2bf(wb.z+eb.z); r[7]=f2bf(wb.w+eb.w);
    return r;
}
__device__ __forceinline__ short8 mkbfw(float4 wa, float4 wb) {
    short8 r;
    r[0]=f2bf(wa.x); r[1]=f2bf(wa.y); r[2]=f2bf(wa.z); r[3]=f2bf(wa.w);
    r[4]=f2bf(wb.x); r[5]=f2bf(wb.y); r[6]=f2bf(wb.z); r[7]=f2bf(wb.w);
    return r;
}

// ---------------------------------------------------------------------------
// Prep: flat elementwise (R6 lesson).
//   blocks [0,1536):      Wt[n][k] = [amat_W; cont_W; 0]^T   (f32, k-contig)
//   blocks [1536,1920):   Xt[c][k] = [z | cont | 0]          (bf16)
//   block  1920:          perm/cnt build (pad slots pre-zeroed -> Xt[0])
// ---------------------------------------------------------------------------
__global__ __launch_bounds__(256) void k_prep(
    const float* __restrict__ z, const int* __restrict__ idx,
    const float* __restrict__ cont, const float* __restrict__ amat_W,
    const float* __restrict__ cont_W,
    int* __restrict__ cnt_ws, int* __restrict__ perm_ws,
    unsigned short* __restrict__ Xt, float* __restrict__ Wt)
{
    const int bid = blockIdx.x, tid = threadIdx.x;

    if (bid < WT_BLOCKS) {
        const int i = bid * 256 + tid;        // writes coalesced (k fastest)
        const int n = i / KTOT, k = i - n * KTOT;
        float v = 0.f;
        if (k < NIN)              v = amat_W[k * NOUT + n];
        else if (k < NIN + NCONT) v = cont_W[(k - NIN) * NOUT + n];
        Wt[i] = v;
    } else if (bid < WT_BLOCKS + XT_BLOCKS) {
        const int i = (bid - WT_BLOCKS) * 256 + tid;
        const int c = i / KTOT, k = i - c * KTOT;
        float v = 0.f;
        if (k < NIN)              v = z[c * NIN + k];
        else if (k < NIN + NCONT) v = cont[c * NCONT + (k - NIN)];
        Xt[i] = (unsigned short)f2bf(v);
    } else {                                  // perm / cnt (one block)
        __shared__ int lcnt[NBATCH];
        if (tid < NBATCH) lcnt[tid] = 0;
        for (int i = tid; i < NBATCH * PCAP; i += 256) perm_ws[i] = 0;
        __syncthreads();
        for (int c = tid; c < B_SZ; c += 256) {
            const int b = idx[c];
            const int p = atomicAdd(&lcnt[b], 1);
            if (p < PCAP) perm_ws[b * PCAP + p] = c;
        }
        __syncthreads();
        if (tid < NBATCH) cnt_ws[tid] = min(lcnt[tid], PCAP);
    }
}

// ---------------------------------------------------------------------------
// Main GEMM. R7-R9 lesson: any design whose MLP depends on the register
// allocator keeping loads live loses (compiler re-clusters load->use to
// minimize pressure; VGPR reported 28-68 across 5 attempts, ~1.35 TB/s).
// Escape: global_load_lds DMA whose in-flight depth is allocation-
// independent (m97-proven pattern on this chip).
//
// Block = (batch b, 256-n chunk), 256 thr. Stage the block's whole embed_A
// slice (4 tiles x 64n x 64k f32 = 64 KB) via 16 upfront gload_lds(16B);
// 512 resident blocks x 64 KB = 32 MB in flight -> BW-saturated by
// construction. One vmcnt(0)+barrier, then 4 compute iterations.
// Bank conflicts (256B row stride => single bank): rule-#21 swizzle —
// linear LDS dest + pre-swizzled SOURCE off^=((off>>8)&7)<<4, same XOR on
// reads -> 2-way (free, m136).
// Frag layouts: A lane&15=m, k=(lane>>4)*8+j ; B lane&15=n, same k ;
// C col=lane&15, row=(lane>>4)*4+r  [m89-verified, R7-validated].
// ---------------------------------------------------------------------------
__global__ __launch_bounds__(256) void k_gemm(
    const float* __restrict__ embed_A,
    const float* __restrict__ embed_h3,
    const unsigned short* __restrict__ Xt,
    const float* __restrict__ Wt,
    const int* __restrict__ cnt_ws,
    const int* __restrict__ perm_ws,
    float* __restrict__ out)
{
    __shared__ float E[4 * 64 * 64];              // 64 KB, swizzled storage
    const int tid  = threadIdx.x;
    const int w    = tid >> 6;                    // wave 0..3
    const int lane = tid & 63;
    const int nl = lane & 15, kq = lane >> 4;
    const int b    = blockIdx.y;
    const int nbase = blockIdx.x * 256;

    const int cnt = cnt_ws[b];                    // wave-uniform
    if (cnt == 0) return;
    const int ntiles = (cnt + 15) >> 4;
    const int* pb = perm_ws + b * PCAP;
    const int k0 = kq * 8;

    // ---- stage 64 KB of embed_A: fire-and-forget DMA, source pre-swizzled
    const char* src = (const char*)(embed_A + (size_t)(b * NOUT + nbase) * NIN);
    #pragma unroll
    for (int g = 0; g < 16; ++g) {
        const int off = g * 4096 + tid * 16;      // linear byte in E
        const int swz = off ^ (((off >> 8) & 7) << 4);
        __builtin_amdgcn_global_load_lds(
            (const __attribute__((address_space(1))) void*)(src + swz),
            (__attribute__((address_space(3))) void*)((char*)E + g * 4096 + w * 1024),
            16, 0, 0);
    }

    // ---- A-fragments + store rows: once per BLOCK (R7 did this per wave)
    const int  c0  = pb[nl];
    const int4 pv0 = *(const int4*)(pb + kq * 4);
    const short8 a00 = *(const short8*)(Xt + c0 * KTOT + k0);
    const short8 a01 = *(const short8*)(Xt + c0 * KTOT + 32 + k0);
    const short8 a02 = *(const short8*)(Xt + c0 * KTOT + 64 + k0);
    int  c1 = 0, c2 = 0;
    int4 pv1 = {0,0,0,0}, pv2 = {0,0,0,0};
    short8 a10 = {}, a11 = {}, a12 = {}, a20 = {}, a21 = {}, a22 = {};
    if (ntiles > 1) {                             // uniform branch
        c1  = pb[16 + nl];
        pv1 = *(const int4*)(pb + 16 + kq * 4);
        a10 = *(const short8*)(Xt + c1 * KTOT + k0);
        a11 = *(const short8*)(Xt + c1 * KTOT + 32 + k0);
        a12 = *(const short8*)(Xt + c1 * KTOT + 64 + k0);
    }
    if (ntiles > 2) {
        c2  = pb[32 + nl];
        pv2 = *(const int4*)(pb + 32 + kq * 4);
        a20 = *(const short8*)(Xt + c2 * KTOT + k0);
        a21 = *(const short8*)(Xt + c2 * KTOT + 32 + k0);
        a22 = *(const short8*)(Xt + c2 * KTOT + 64 + k0);
    }

    asm volatile("s_waitcnt vmcnt(0)" ::: "memory");
    __syncthreads();                              // E fully resident

    // ---- 4 compute iterations over 64-n tiles; wave owns 16 n per tile
    #pragma unroll
    for (int it = 0; it < 4; ++it) {
        const int n_loc = w * 16 + nl;            // 0..63 within tile
        const int n = nbase + it * 64 + n_loc;
        const int ebase = it * 16384 + n_loc * 256;
        const int sw = (n_loc & 7) << 4;
        const float4 e00 = *(const float4*)((const char*)E + ((ebase +       kq*32     ) ^ sw));
        const float4 e01 = *(const float4*)((const char*)E + ((ebase +       kq*32 + 16) ^ sw));
        const float4 e10 = *(const float4*)((const char*)E + ((ebase + 128 + kq*32     ) ^ sw));
        const float4 e11 = *(const float4*)((const char*)E + ((ebase + 128 + kq*32 + 16) ^ sw));

        const float* wb = Wt + n * KTOT;          // L2-hot (1.5 MB shared)
        const float4 w00 = *(const float4*)(wb + k0);
        const float4 w01 = *(const float4*)(wb + k0 + 4);
        const float4 w10 = *(const float4*)(wb + 32 + k0);
        const float4 w11 = *(const float4*)(wb + 32 + k0 + 4);
        const float4 w20 = *(const float4*)(wb + 64 + k0);
        const float4 w21 = *(const float4*)(wb + 64 + k0 + 4);
        const float  h3v = embed_h3[b * NOUT + n];

        const short8 bf0 = mkbf(w00, w01, e00, e01);
        const short8 bf1 = mkbf(w10, w11, e10, e11);
        const short8 bf2 = mkbfw(w20, w21);       // k>=64: no embed term

        f32x4 acc0 = {0,0,0,0};
        acc0 = __builtin_amdgcn_mfma_f32_16x16x32_bf16(a00, bf0, acc0, 0, 0, 0);
        acc0 = __builtin_amdgcn_mfma_f32_16x16x32_bf16(a01, bf1, acc0, 0, 0, 0);
        acc0 = __builtin_amdgcn_mfma_f32_16x16x32_bf16(a02, bf2, acc0, 0, 0, 0);
        {
            const int sb = kq * 4;
            if (sb + 0 < cnt) out[(size_t)pv0.x * NOUT + n] = acc0[0] + h3v;
            if (sb + 1 < cnt) out[(size_t)pv0.y * NOUT + n] = acc0[1] + h3v;
            if (sb + 2 < cnt) out[(size_t)pv0.z * NOUT + n] = acc0[2] + h3v;
            if (sb + 3 < cnt) out[(size_t)pv0.w * NOUT + n] = acc0[3] + h3v;
        }
        if (ntiles > 1) {
            f32x4 acc1 = {0,0,0,0};
            acc1 = __builtin_amdgcn_mfma_f32_16x16x32_bf16(a10, bf0, acc1, 0, 0, 0);
            acc1 = __builtin_amdgcn_mfma_f32_16x16x32_bf16(a11, bf1, acc1, 0, 0, 0);
            acc1 = __builtin_amdgcn_mfma_f32_16x16x32_bf16(a12, bf2, acc1, 0, 0, 0);
            const int sb = 16 + kq * 4;
            if (sb + 0 < cnt) out[(size_t)pv1.x * NOUT + n] = acc1[0] + h3v;
            if (sb + 1 < cnt) out[(size_t)pv1.y * NOUT + n] = acc1[1] + h3v;
            if (sb + 2 < cnt) out[(size_t)pv1.z * NOUT + n] = acc1[2] + h3v;
            if (sb + 3 < cnt) out[(size_t)pv1.w * NOUT + n] = acc1[3] + h3v;
        }
        if (ntiles > 2) {
            f32x4 acc2 = {0,0,0,0};
            acc2 = __builtin_amdgcn_mfma_f32_16x16x32_bf16(a20, bf0, acc2, 0, 0, 0);
            acc2 = __builtin_amdgcn_mfma_f32_16x16x32_bf16(a21, bf1, acc2, 0, 0, 0);
            acc2 = __builtin_amdgcn_mfma_f32_16x16x32_bf16(a22, bf2, acc2, 0, 0, 0);
            const int sb = 32 + kq * 4;
            if (sb + 0 < cnt) out[(size_t)pv2.x * NOUT + n] = acc2[0] + h3v;
            if (sb + 1 < cnt) out[(size_t)pv2.y * NOUT + n] = acc2[1] + h3v;
            if (sb + 2 < cnt) out[(size_t)pv2.z * NOUT + n] = acc2[2] + h3v;
            if (sb + 3 < cnt) out[(size_t)pv2.w * NOUT + n] = acc2[3] + h3v;
        }
    }
}

// ---------------------------------------------------------------------------
// Softmax: in-place row softmax * size_factor; blocks 0..15 also write
// inverse_dispersion = exp(px_r).
// ---------------------------------------------------------------------------
__global__ __launch_bounds__(256) void k_softmax(
    float*       __restrict__ out,
    const float* __restrict__ sf,
    const float* __restrict__ px_r)
{
    const int c   = blockIdx.x;
    const int tid = threadIdx.x;
    float4* row4 = reinterpret_cast<float4*>(out + (size_t)c * NOUT);

    float4 v[4];
    #pragma unroll
    for (int j = 0; j < 4; ++j) v[j] = row4[j * 256 + tid];

    float m = -3.4e38f;
    #pragma unroll
    for (int j = 0; j < 4; ++j)
        m = fmaxf(fmaxf(fmaxf(m, v[j].x), fmaxf(v[j].y, v[j].z)), v[j].w);

    #pragma unroll
    for (int off = 32; off > 0; off >>= 1)
        m = fmaxf(m, __shfl_xor(m, off, 64));

    __shared__ float s_red[8];
    const int wave = tid >> 6;
    const int lane = tid & 63;
    if (lane == 0) s_red[wave] = m;
    __syncthreads();
    m = fmaxf(fmaxf(s_red[0], s_red[1]), fmaxf(s_red[2], s_red[3]));

    float s = 0.f;
    #pragma unroll
    for (int j = 0; j < 4; ++j) {
        v[j].x = __expf(v[j].x - m); v[j].y = __expf(v[j].y - m);
        v[j].z = __expf(v[j].z - m); v[j].w = __expf(v[j].w - m);
        s += v[j].x + v[j].y + v[j].z + v[j].w;
    }
    #pragma unroll
    for (int off = 32; off > 0; off >>= 1)
        s += __shfl_xor(s, off, 64);
    if (lane == 0) s_red[4 + wave] = s;
    __syncthreads();
    s = s_red[4] + s_red[5] + s_red[6] + s_red[7];

    const float scale = sf[c] / s;
    #pragma unroll
    for (int j = 0; j < 4; ++j) {
        v[j].x *= scale; v[j].y *= scale; v[j].z *= scale; v[j].w *= scale;
        row4[j * 256 + tid] = v[j];
    }

    if (c < NOUT / 256) {                 // 16 blocks cover px_r
        const int i = c * 256 + tid;
        out[(size_t)B_SZ * NOUT + i] = __expf(px_r[i]);
    }
}

// ---------------------------------------------------------------------------
extern "C" void kernel_launch(void* const* d_in, const int* in_sizes, int n_in,
                              void* d_out, int out_size, void* d_ws, size_t ws_size,
                              hipStream_t stream)
{
    const float* z       = (const float*)d_in[0];
    const int*   idx     = (const int*)  d_in[1];
    const float* sf      = (const float*)d_in[2];
    const float* cont    = (const float*)d_in[3];
    const float* amat_W  = (const float*)d_in[4];
    const float* embed_A = (const float*)d_in[5];
    const float* eh3     = (const float*)d_in[6];
    const float* cont_W  = (const float*)d_in[7];
    const float* px_r    = (const float*)d_in[8];
    float* out = (float*)d_out;

    // ws layout (bytes): cnt[64] @0 | perm[64*48] @256 | Xt bf16 @16384
    //                    | Wt f32 @212992 | total ~1.75 MB
    char* ws = (char*)d_ws;
    int*            cnt_ws  = (int*)ws;
    int*            perm_ws = (int*)(ws + 256);
    unsigned short* Xt      = (unsigned short*)(ws + 16384);
    float*          Wt      = (float*)(ws + 212992);

    k_prep<<<WT_BLOCKS + XT_BLOCKS + 1, 256, 0, stream>>>(
        z, idx, cont, amat_W, cont_W, cnt_ws, perm_ws, Xt, Wt);

    dim3 grid1(NOUT / 256, NBATCH);       // (16, 64) = 1024 blocks x 4 waves
    k_gemm<<<grid1, 256, 0, stream>>>(embed_A, eh3, Xt, Wt,
                                      cnt_ws, perm_ws, out);

    k_softmax<<<B_SZ, 256, 0, stream>>>(out, sf, px_r);
}

// Round 11
// 47.040 us; speedup vs baseline: 1.0092x; 1.0092x over previous
//
#include <hip/hip_runtime.h>
#include <hip/hip_bf16.h>

#define B_SZ   1024
#define NIN    64
#define NOUT   4096
#define NBATCH 64
#define NCONT  16
#define KTOT   96      // z(64) | cont(16) | zero-pad(16)
#define PCAP   48      // per-batch sample capacity (Poisson(16) max ~32)

#define WT_ELEMS   (NOUT * KTOT)              // 393216
#define XT_ELEMS   (B_SZ * KTOT)              // 98304
#define WT_BLOCKS  (WT_ELEMS / 256)           // 1536
#define XT_BLOCKS  (XT_ELEMS / 256)           // 384

typedef __attribute__((ext_vector_type(8))) short short8;   // 8 bf16 = 4 VGPR
typedef __attribute__((ext_vector_type(4))) float f32x4;

// f32 -> bf16 bits, round-to-nearest-even
__device__ __forceinline__ short f2bf(float f) {
    unsigned u = __float_as_uint(f);
    return (short)((u + 0x7FFFu + ((u >> 16) & 1u)) >> 16);
}

__device__ __forceinline__ short8 mkbf(float4 wa, float4 wb, float4 ea, float4 eb) {
    short8 r;
    r[0]=f2bf(wa.x+ea.x); r[1]=f2bf(wa.y+ea.y); r[2]=f2bf(wa.z+ea.z); r[3]=f2bf(wa.w+ea.w);
    r[4]=f2bf(wb.x+eb.x); r[5]=f2bf(wb.y+eb.y); r[6]=f2bf(wb.z+eb.z); r[7]=f2bf(wb.w+eb.w);
    return r;
}
__device__ __forceinline__ short8 mkbfw(float4 wa, float4 wb) {
    short8 r;
    r[0]=f2bf(wa.x); r[1]=f2bf(wa.y); r[2]=f2bf(wa.z); r[3]=f2bf(wa.w);
    r[4]=f2bf(wb.x); r[5]=f2bf(wb.y); r[6]=f2bf(wb.z); r[7]=f2bf(wb.w);
    return r;
}

// ---------------------------------------------------------------------------
// Prep: flat elementwise (R6 lesson).
// ---------------------------------------------------------------------------
__global__ __launch_bounds__(256) void k_prep(
    const float* __restrict__ z, const int* __restrict__ idx,
    const float* __restrict__ cont, const float* __restrict__ amat_W,
    const float* __restrict__ cont_W,
    int* __restrict__ cnt_ws, int* __restrict__ perm_ws,
    unsigned short* __restrict__ Xt, float* __restrict__ Wt)
{
    const int bid = blockIdx.x, tid = threadIdx.x;

    if (bid < WT_BLOCKS) {
        const int i = bid * 256 + tid;        // writes coalesced (k fastest)
        const int n = i / KTOT, k = i - n * KTOT;
        float v = 0.f;
        if (k < NIN)              v = amat_W[k * NOUT + n];
        else if (k < NIN + NCONT) v = cont_W[(k - NIN) * NOUT + n];
        Wt[i] = v;
    } else if (bid < WT_BLOCKS + XT_BLOCKS) {
        const int i = (bid - WT_BLOCKS) * 256 + tid;
        const int c = i / KTOT, k = i - c * KTOT;
        float v = 0.f;
        if (k < NIN)              v = z[c * NIN + k];
        else if (k < NIN + NCONT) v = cont[c * NCONT + (k - NIN)];
        Xt[i] = (unsigned short)f2bf(v);
    } else {                                  // perm / cnt (one block)
        __shared__ int lcnt[NBATCH];
        if (tid < NBATCH) lcnt[tid] = 0;
        for (int i = tid; i < NBATCH * PCAP; i += 256) perm_ws[i] = 0;
        __syncthreads();
        for (int c = tid; c < B_SZ; c += 256) {
            const int b = idx[c];
            const int p = atomicAdd(&lcnt[b], 1);
            if (p < PCAP) perm_ws[b * PCAP + p] = c;
        }
        __syncthreads();
        if (tid < NBATCH) cnt_ws[tid] = min(lcnt[tid], PCAP);
    }
}

// ---------------------------------------------------------------------------
// Main GEMM.
// R10 post-mortem (wave-lifetime math): ~29 memory ops/wave x ~800ns EACH =
// 19us wave lifetime -> ops ran SERIAL. Causes: (1) source-swizzle shattered
// each 1KB gload_lds into 64 scattered 16B requests (miss-queue overflow ->
// serialization; also the 262K LDS write conflicts); (2) pb[nl] issued AFTER
// the DMAs -> compiler's auto-vmcnt for the dependent a-frag address drains
// the whole in-order DMA queue.
// Fix: LINEAR contiguous DMA (1KB/instr, 16x64B lines); LDS bank conflicts
// handled by +16B pad per 4-row GROUP via per-instruction dest base
// (gg*1040) - legal since only the lane offset must be contiguous; and all
// independent/dependent VMEM issued BEFORE the DMA group (sched_barrier
// fence) so nothing ever waits on the DMA queue except the final vmcnt(0).
// Frag layouts: A lane&15=m, k=(lane>>4)*8+j ; B lane&15=n, same k ;
// C col=lane&15, row=(lane>>4)*4+r  [m89-verified, R7/R10-validated].
// ---------------------------------------------------------------------------
__global__ __launch_bounds__(256) void k_gemm(
    const float* __restrict__ embed_A,
    const float* __restrict__ embed_h3,
    const unsigned short* __restrict__ Xt,
    const float* __restrict__ Wt,
    const int* __restrict__ cnt_ws,
    const int* __restrict__ perm_ws,
    float* __restrict__ out)
{
    __shared__ __align__(16) char E[64 * 1040];   // 256 rows, +16B pad / 4-row group
    const int tid  = threadIdx.x;
    const int w    = tid >> 6;                    // wave 0..3
    const int lane = tid & 63;
    const int nl = lane & 15, kq = lane >> 4;
    const int b    = blockIdx.y;
    const int nbase = blockIdx.x * 256;

    const int cnt = cnt_ws[b];                    // wave-uniform
    if (cnt == 0) return;
    const int ntiles = (cnt + 15) >> 4;
    const int* pb = perm_ws + b * PCAP;
    const int k0 = kq * 8;

    // ---- phase 1: ALL register loads (independent first, then dependent) ---
    const int  c0  = pb[nl];
    const int4 pv0 = *(const int4*)(pb + kq * 4);
    const short8 a00 = *(const short8*)(Xt + c0 * KTOT + k0);
    const short8 a01 = *(const short8*)(Xt + c0 * KTOT + 32 + k0);
    const short8 a02 = *(const short8*)(Xt + c0 * KTOT + 64 + k0);
    int  c1 = 0, c2 = 0;
    int4 pv1 = {0,0,0,0}, pv2 = {0,0,0,0};
    short8 a10 = {}, a11 = {}, a12 = {}, a20 = {}, a21 = {}, a22 = {};
    if (ntiles > 1) {                             // uniform branch
        c1  = pb[16 + nl];
        pv1 = *(const int4*)(pb + 16 + kq * 4);
        a10 = *(const short8*)(Xt + c1 * KTOT + k0);
        a11 = *(const short8*)(Xt + c1 * KTOT + 32 + k0);
        a12 = *(const short8*)(Xt + c1 * KTOT + 64 + k0);
    }
    if (ntiles > 2) {
        c2  = pb[32 + nl];
        pv2 = *(const int4*)(pb + 32 + kq * 4);
        a20 = *(const short8*)(Xt + c2 * KTOT + k0);
        a21 = *(const short8*)(Xt + c2 * KTOT + 32 + k0);
        a22 = *(const short8*)(Xt + c2 * KTOT + 64 + k0);
    }
    __builtin_amdgcn_sched_barrier(0);            // reg loads stay ABOVE DMA

    // ---- phase 2: stage 64KB embed_A, linear contiguous 1KB per instr ------
    const char* srcb = (const char*)(embed_A + (size_t)(b * NOUT + nbase) * NIN);
    #pragma unroll
    for (int g = 0; g < 16; ++g) {
        const int gg = g * 4 + w;                 // 4-row group, wave-uniform
        __builtin_amdgcn_global_load_lds(
            (const __attribute__((address_space(1))) void*)(srcb + gg * 1024 + lane * 16),
            (__attribute__((address_space(3))) void*)(E + gg * 1040),
            16, 0, 0);
    }
    asm volatile("s_waitcnt vmcnt(0)" ::: "memory");
    __builtin_amdgcn_sched_barrier(0);
    __syncthreads();                              // E fully resident

    // ---- phase 3: 4 compute iterations over 64-n tiles ---------------------
    #pragma unroll
    for (int it = 0; it < 4; ++it) {
        const int n_loc = w * 16 + nl;            // 0..63 within tile
        const int n = nbase + it * 64 + n_loc;
        const int r = it * 64 + n_loc;            // LDS row
        const char* rowp = E + (r >> 2) * 1040 + (r & 3) * 256;
        const float4 e00 = *(const float4*)(rowp + kq * 32);
        const float4 e01 = *(const float4*)(rowp + kq * 32 + 16);
        const float4 e10 = *(const float4*)(rowp + 128 + kq * 32);
        const float4 e11 = *(const float4*)(rowp + 128 + kq * 32 + 16);

        const float* wb = Wt + n * KTOT;          // L2-hot (per-XCD resident)
        const float4 w00 = *(const float4*)(wb + k0);
        const float4 w01 = *(const float4*)(wb + k0 + 4);
        const float4 w10 = *(const float4*)(wb + 32 + k0);
        const float4 w11 = *(const float4*)(wb + 32 + k0 + 4);
        const float4 w20 = *(const float4*)(wb + 64 + k0);
        const float4 w21 = *(const float4*)(wb + 64 + k0 + 4);
        const float  h3v = embed_h3[b * NOUT + n];

        const short8 bf0 = mkbf(w00, w01, e00, e01);
        const short8 bf1 = mkbf(w10, w11, e10, e11);
        const short8 bf2 = mkbfw(w20, w21);       // k>=64: no embed term

        f32x4 acc0 = {0,0,0,0};
        acc0 = __builtin_amdgcn_mfma_f32_16x16x32_bf16(a00, bf0, acc0, 0, 0, 0);
        acc0 = __builtin_amdgcn_mfma_f32_16x16x32_bf16(a01, bf1, acc0, 0, 0, 0);
        acc0 = __builtin_amdgcn_mfma_f32_16x16x32_bf16(a02, bf2, acc0, 0, 0, 0);
        {
            const int sb = kq * 4;
            if (sb + 0 < cnt) out[(size_t)pv0.x * NOUT + n] = acc0[0] + h3v;
            if (sb + 1 < cnt) out[(size_t)pv0.y * NOUT + n] = acc0[1] + h3v;
            if (sb + 2 < cnt) out[(size_t)pv0.z * NOUT + n] = acc0[2] + h3v;
            if (sb + 3 < cnt) out[(size_t)pv0.w * NOUT + n] = acc0[3] + h3v;
        }
        if (ntiles > 1) {
            f32x4 acc1 = {0,0,0,0};
            acc1 = __builtin_amdgcn_mfma_f32_16x16x32_bf16(a10, bf0, acc1, 0, 0, 0);
            acc1 = __builtin_amdgcn_mfma_f32_16x16x32_bf16(a11, bf1, acc1, 0, 0, 0);
            acc1 = __builtin_amdgcn_mfma_f32_16x16x32_bf16(a12, bf2, acc1, 0, 0, 0);
            const int sb = 16 + kq * 4;
            if (sb + 0 < cnt) out[(size_t)pv1.x * NOUT + n] = acc1[0] + h3v;
            if (sb + 1 < cnt) out[(size_t)pv1.y * NOUT + n] = acc1[1] + h3v;
            if (sb + 2 < cnt) out[(size_t)pv1.z * NOUT + n] = acc1[2] + h3v;
            if (sb + 3 < cnt) out[(size_t)pv1.w * NOUT + n] = acc1[3] + h3v;
        }
        if (ntiles > 2) {
            f32x4 acc2 = {0,0,0,0};
            acc2 = __builtin_amdgcn_mfma_f32_16x16x32_bf16(a20, bf0, acc2, 0, 0, 0);
            acc2 = __builtin_amdgcn_mfma_f32_16x16x32_bf16(a21, bf1, acc2, 0, 0, 0);
            acc2 = __builtin_amdgcn_mfma_f32_16x16x32_bf16(a22, bf2, acc2, 0, 0, 0);
            const int sb = 32 + kq * 4;
            if (sb + 0 < cnt) out[(size_t)pv2.x * NOUT + n] = acc2[0] + h3v;
            if (sb + 1 < cnt) out[(size_t)pv2.y * NOUT + n] = acc2[1] + h3v;
            if (sb + 2 < cnt) out[(size_t)pv2.z * NOUT + n] = acc2[2] + h3v;
            if (sb + 3 < cnt) out[(size_t)pv2.w * NOUT + n] = acc2[3] + h3v;
        }
    }
}

// ---------------------------------------------------------------------------
// Softmax: in-place row softmax * size_factor; blocks 0..15 also write
// inverse_dispersion = exp(px_r).
// ---------------------------------------------------------------------------
__global__ __launch_bounds__(256) void k_softmax(
    float*       __restrict__ out,
    const float* __restrict__ sf,
    const float* __restrict__ px_r)
{
    const int c   = blockIdx.x;
    const int tid = threadIdx.x;
    float4* row4 = reinterpret_cast<float4*>(out + (size_t)c * NOUT);

    float4 v[4];
    #pragma unroll
    for (int j = 0; j < 4; ++j) v[j] = row4[j * 256 + tid];

    float m = -3.4e38f;
    #pragma unroll
    for (int j = 0; j < 4; ++j)
        m = fmaxf(fmaxf(fmaxf(m, v[j].x), fmaxf(v[j].y, v[j].z)), v[j].w);

    #pragma unroll
    for (int off = 32; off > 0; off >>= 1)
        m = fmaxf(m, __shfl_xor(m, off, 64));

    __shared__ float s_red[8];
    const int wave = tid >> 6;
    const int lane = tid & 63;
    if (lane == 0) s_red[wave] = m;
    __syncthreads();
    m = fmaxf(fmaxf(s_red[0], s_red[1]), fmaxf(s_red[2], s_red[3]));

    float s = 0.f;
    #pragma unroll
    for (int j = 0; j < 4; ++j) {
        v[j].x = __expf(v[j].x - m); v[j].y = __expf(v[j].y - m);
        v[j].z = __expf(v[j].z - m); v[j].w = __expf(v[j].w - m);
        s += v[j].x + v[j].y + v[j].z + v[j].w;
    }
    #pragma unroll
    for (int off = 32; off > 0; off >>= 1)
        s += __shfl_xor(s, off, 64);
    if (lane == 0) s_red[4 + wave] = s;
    __syncthreads();
    s = s_red[4] + s_red[5] + s_red[6] + s_red[7];

    const float scale = sf[c] / s;
    #pragma unroll
    for (int j = 0; j < 4; ++j) {
        v[j].x *= scale; v[j].y *= scale; v[j].z *= scale; v[j].w *= scale;
        row4[j * 256 + tid] = v[j];
    }

    if (c < NOUT / 256) {                 // 16 blocks cover px_r
        const int i = c * 256 + tid;
        out[(size_t)B_SZ * NOUT + i] = __expf(px_r[i]);
    }
}

// ---------------------------------------------------------------------------
extern "C" void kernel_launch(void* const* d_in, const int* in_sizes, int n_in,
                              void* d_out, int out_size, void* d_ws, size_t ws_size,
                              hipStream_t stream)
{
    const float* z       = (const float*)d_in[0];
    const int*   idx     = (const int*)  d_in[1];
    const float* sf      = (const float*)d_in[2];
    const float* cont    = (const float*)d_in[3];
    const float* amat_W  = (const float*)d_in[4];
    const float* embed_A = (const float*)d_in[5];
    const float* eh3     = (const float*)d_in[6];
    const float* cont_W  = (const float*)d_in[7];
    const float* px_r    = (const float*)d_in[8];
    float* out = (float*)d_out;

    // ws layout (bytes): cnt[64] @0 | perm[64*48] @256 | Xt bf16 @16384
    //                    | Wt f32 @212992 | total ~1.75 MB
    char* ws = (char*)d_ws;
    int*            cnt_ws  = (int*)ws;
    int*            perm_ws = (int*)(ws + 256);
    unsigned short* Xt      = (unsigned short*)(ws + 16384);
    float*          Wt      = (float*)(ws + 212992);

    k_prep<<<WT_BLOCKS + XT_BLOCKS + 1, 256, 0, stream>>>(
        z, idx, cont, amat_W, cont_W, cnt_ws, perm_ws, Xt, Wt);

    dim3 grid1(NOUT / 256, NBATCH);       // (16, 64) = 1024 blocks x 4 waves
    k_gemm<<<grid1, 256, 0, stream>>>(embed_A, eh3, Xt, Wt,
                                      cnt_ws, perm_ws, out);

    k_softmax<<<B_SZ, 256, 0, stream>>>(out, sf, px_r);
}

// Round 12
// 46.321 us; speedup vs baseline: 1.0248x; 1.0155x over previous
//
#include <hip/hip_runtime.h>
#include <hip/hip_bf16.h>

#define B_SZ   1024
#define NIN    64
#define NOUT   4096
#define NBATCH 64
#define NCONT  16
#define KTOT   96      // z(64) | cont(16) | zero-pad(16)
#define PCAP   48      // per-batch sample capacity (Poisson(16) max ~32)

#define WT_ELEMS   (NOUT * KTOT)              // 393216
#define XT_ELEMS   (B_SZ * KTOT)              // 98304
#define WT_BLOCKS  (WT_ELEMS / 256)           // 1536
#define XT_BLOCKS  (XT_ELEMS / 256)           // 384

typedef __attribute__((ext_vector_type(8))) short short8;   // 8 bf16 = 4 VGPR
typedef __attribute__((ext_vector_type(4))) float f32x4;

// f32 -> bf16 bits, round-to-nearest-even
__device__ __forceinline__ short f2bf(float f) {
    unsigned u = __float_as_uint(f);
    return (short)((u + 0x7FFFu + ((u >> 16) & 1u)) >> 16);
}

__device__ __forceinline__ short8 mkbf(float4 wa, float4 wb, float4 ea, float4 eb) {
    short8 r;
    r[0]=f2bf(wa.x+ea.x); r[1]=f2bf(wa.y+ea.y); r[2]=f2bf(wa.z+ea.z); r[3]=f2bf(wa.w+ea.w);
    r[4]=f2bf(wb.x+eb.x); r[5]=f2bf(wb.y+eb.y); r[6]=f2bf(wb.z+eb.z); r[7]=f2bf(wb.w+eb.w);
    return r;
}
__device__ __forceinline__ short8 mkbfw(float4 wa, float4 wb) {
    short8 r;
    r[0]=f2bf(wa.x); r[1]=f2bf(wa.y); r[2]=f2bf(wa.z); r[3]=f2bf(wa.w);
    r[4]=f2bf(wb.x); r[5]=f2bf(wb.y); r[6]=f2bf(wb.z); r[7]=f2bf(wb.w);
    return r;
}

// ---------------------------------------------------------------------------
// Prep: flat elementwise (R6 lesson).
// ---------------------------------------------------------------------------
__global__ __launch_bounds__(256) void k_prep(
    const float* __restrict__ z, const int* __restrict__ idx,
    const float* __restrict__ cont, const float* __restrict__ amat_W,
    const float* __restrict__ cont_W,
    int* __restrict__ cnt_ws, int* __restrict__ perm_ws,
    unsigned short* __restrict__ Xt, float* __restrict__ Wt)
{
    const int bid = blockIdx.x, tid = threadIdx.x;

    if (bid < WT_BLOCKS) {
        const int i = bid * 256 + tid;        // writes coalesced (k fastest)
        const int n = i / KTOT, k = i - n * KTOT;
        float v = 0.f;
        if (k < NIN)              v = amat_W[k * NOUT + n];
        else if (k < NIN + NCONT) v = cont_W[(k - NIN) * NOUT + n];
        Wt[i] = v;
    } else if (bid < WT_BLOCKS + XT_BLOCKS) {
        const int i = (bid - WT_BLOCKS) * 256 + tid;
        const int c = i / KTOT, k = i - c * KTOT;
        float v = 0.f;
        if (k < NIN)              v = z[c * NIN + k];
        else if (k < NIN + NCONT) v = cont[c * NCONT + (k - NIN)];
        Xt[i] = (unsigned short)f2bf(v);
    } else {                                  // perm / cnt (one block)
        __shared__ int lcnt[NBATCH];
        if (tid < NBATCH) lcnt[tid] = 0;
        for (int i = tid; i < NBATCH * PCAP; i += 256) perm_ws[i] = 0;
        __syncthreads();
        for (int c = tid; c < B_SZ; c += 256) {
            const int b = idx[c];
            const int p = atomicAdd(&lcnt[b], 1);
            if (p < PCAP) perm_ws[b * PCAP + p] = c;
        }
        __syncthreads();
        if (tid < NBATCH) cnt_ws[tid] = min(lcnt[tid], PCAP);
    }
}

// ---------------------------------------------------------------------------
// Main: per (16-col n-tile, batch b): C[m<=48][n16] = Xt_b @ (Wt + embed_A_b)
// via mfma_f32_16x16x32_bf16.
//
// R7-R11 lesson: FOUR different staging mechanisms (register named-loads,
// waves_per_eu, swizzled DMA, linear DMA) all land at 1.36 TB/s == ~1 memory
// op in flight per CU. Compiler-controlled issue/wait order is the common
// factor. This version puts ALL 19 VMEM loads of the wave in ONE asm
// volatile block (back-to-back issue, single s_waitcnt vmcnt(0) at the end,
// early-clobber outputs) - the compiler cannot re-cluster, serialize, or
// insert waits inside it, and the allocator MUST keep ~75 result VGPRs live.
// SGPR-base + u32 voffset + offset: immediates keep address VGPRs to 6.
// Frag layouts: A lane&15=m, k=(lane>>4)*8+j ; B lane&15=n, same k ;
// C col=lane&15, row=(lane>>4)*4+r  [m89-verified, R7-validated].
// ---------------------------------------------------------------------------
__global__ __launch_bounds__(64) void k_mfma(
    const float* __restrict__ embed_A,
    const float* __restrict__ embed_h3,
    const unsigned short* __restrict__ Xt,
    const float* __restrict__ Wt,
    const int* __restrict__ cnt_ws,
    const int* __restrict__ perm_ws,
    float* __restrict__ out)
{
    const int lane = threadIdx.x;
    const int nl = lane & 15, kq = lane >> 4;
    const int n  = blockIdx.x * 16 + nl;
    const int b  = blockIdx.y;
    const int cnt = cnt_ws[b];                    // wave-uniform
    if (cnt == 0) return;
    const int ntiles = (cnt + 15) >> 4;
    const int* pb = perm_ws + b * PCAP;
    const int k0 = kq * 8;

    // dependent indices first (tiny, L2-hot; compiler handles their waits)
    const int c0 = pb[nl];
    const int c1 = pb[16 + nl];     // slot pre-zeroed in prep -> Xt[0], harmless

    const unsigned ow  = (unsigned)((n * KTOT + k0) * 4);
    const unsigned oe  = (unsigned)(((size_t)(b * NOUT + n) * NIN + k0) * 4);
    const unsigned ox0 = (unsigned)((c0 * KTOT + k0) * 2);
    const unsigned ox1 = (unsigned)((c1 * KTOT + k0) * 2);
    const unsigned opv = (unsigned)((b * PCAP + kq * 4) * 4);
    const unsigned oh  = (unsigned)((b * NOUT + n) * 4);

    float4 W00, W01, W10, W11, W20, W21, E00, E01, E10, E11;
    int4   A00, A01, A02, A10, A11, A12, PV0, PV1;
    float  H3;
    asm volatile(
        "global_load_dwordx4 %[w00], %[ow], %[wt]\n\t"
        "global_load_dwordx4 %[w01], %[ow], %[wt] offset:16\n\t"
        "global_load_dwordx4 %[w10], %[ow], %[wt] offset:128\n\t"
        "global_load_dwordx4 %[w11], %[ow], %[wt] offset:144\n\t"
        "global_load_dwordx4 %[w20], %[ow], %[wt] offset:256\n\t"
        "global_load_dwordx4 %[w21], %[ow], %[wt] offset:272\n\t"
        "global_load_dwordx4 %[e00], %[oe], %[ea]\n\t"
        "global_load_dwordx4 %[e01], %[oe], %[ea] offset:16\n\t"
        "global_load_dwordx4 %[e10], %[oe], %[ea] offset:128\n\t"
        "global_load_dwordx4 %[e11], %[oe], %[ea] offset:144\n\t"
        "global_load_dwordx4 %[a00], %[ox0], %[xt]\n\t"
        "global_load_dwordx4 %[a01], %[ox0], %[xt] offset:64\n\t"
        "global_load_dwordx4 %[a02], %[ox0], %[xt] offset:128\n\t"
        "global_load_dwordx4 %[a10], %[ox1], %[xt]\n\t"
        "global_load_dwordx4 %[a11], %[ox1], %[xt] offset:64\n\t"
        "global_load_dwordx4 %[a12], %[ox1], %[xt] offset:128\n\t"
        "global_load_dwordx4 %[pv0], %[opv], %[pm]\n\t"
        "global_load_dwordx4 %[pv1], %[opv], %[pm] offset:64\n\t"
        "global_load_dword   %[h3],  %[oh],  %[hp]\n\t"
        "s_waitcnt vmcnt(0)"
        : [w00]"=&v"(W00), [w01]"=&v"(W01), [w10]"=&v"(W10), [w11]"=&v"(W11),
          [w20]"=&v"(W20), [w21]"=&v"(W21),
          [e00]"=&v"(E00), [e01]"=&v"(E01), [e10]"=&v"(E10), [e11]"=&v"(E11),
          [a00]"=&v"(A00), [a01]"=&v"(A01), [a02]"=&v"(A02),
          [a10]"=&v"(A10), [a11]"=&v"(A11), [a12]"=&v"(A12),
          [pv0]"=&v"(PV0), [pv1]"=&v"(PV1), [h3]"=&v"(H3)
        : [ow]"v"(ow), [oe]"v"(oe), [ox0]"v"(ox0), [ox1]"v"(ox1),
          [opv]"v"(opv), [oh]"v"(oh),
          [wt]"s"(Wt), [ea]"s"(embed_A), [xt]"s"(Xt),
          [pm]"s"(perm_ws), [hp]"s"(embed_h3)
        : "memory");
    __builtin_amdgcn_sched_barrier(0);

    const short8 a00 = *(const short8*)&A00;
    const short8 a01 = *(const short8*)&A01;
    const short8 a02 = *(const short8*)&A02;

    const short8 bf0 = mkbf(W00, W01, E00, E01);
    const short8 bf1 = mkbf(W10, W11, E10, E11);
    const short8 bf2 = mkbfw(W20, W21);           // k>=64: no embed term

    f32x4 acc0 = {0, 0, 0, 0};
    acc0 = __builtin_amdgcn_mfma_f32_16x16x32_bf16(a00, bf0, acc0, 0, 0, 0);
    acc0 = __builtin_amdgcn_mfma_f32_16x16x32_bf16(a01, bf1, acc0, 0, 0, 0);
    acc0 = __builtin_amdgcn_mfma_f32_16x16x32_bf16(a02, bf2, acc0, 0, 0, 0);
    {
        const int sb = kq * 4;
        if (sb + 0 < cnt) out[(size_t)PV0.x * NOUT + n] = acc0[0] + H3;
        if (sb + 1 < cnt) out[(size_t)PV0.y * NOUT + n] = acc0[1] + H3;
        if (sb + 2 < cnt) out[(size_t)PV0.z * NOUT + n] = acc0[2] + H3;
        if (sb + 3 < cnt) out[(size_t)PV0.w * NOUT + n] = acc0[3] + H3;
    }

    if (ntiles > 1) {                             // uniform branch
        const short8 a10 = *(const short8*)&A10;
        const short8 a11 = *(const short8*)&A11;
        const short8 a12 = *(const short8*)&A12;
        f32x4 acc1 = {0, 0, 0, 0};
        acc1 = __builtin_amdgcn_mfma_f32_16x16x32_bf16(a10, bf0, acc1, 0, 0, 0);
        acc1 = __builtin_amdgcn_mfma_f32_16x16x32_bf16(a11, bf1, acc1, 0, 0, 0);
        acc1 = __builtin_amdgcn_mfma_f32_16x16x32_bf16(a12, bf2, acc1, 0, 0, 0);
        const int sb = 16 + kq * 4;
        if (sb + 0 < cnt) out[(size_t)PV1.x * NOUT + n] = acc1[0] + H3;
        if (sb + 1 < cnt) out[(size_t)PV1.y * NOUT + n] = acc1[1] + H3;
        if (sb + 2 < cnt) out[(size_t)PV1.z * NOUT + n] = acc1[2] + H3;
        if (sb + 3 < cnt) out[(size_t)PV1.w * NOUT + n] = acc1[3] + H3;
    }

    if (ntiles > 2) {                             // rare (cnt>32): plain C path
        const int  c2  = pb[32 + nl];
        const int4 pv2 = *(const int4*)(pb + 32 + kq * 4);
        const short8 a20 = *(const short8*)(Xt + c2 * KTOT + k0);
        const short8 a21 = *(const short8*)(Xt + c2 * KTOT + 32 + k0);
        const short8 a22 = *(const short8*)(Xt + c2 * KTOT + 64 + k0);
        f32x4 acc2 = {0, 0, 0, 0};
        acc2 = __builtin_amdgcn_mfma_f32_16x16x32_bf16(a20, bf0, acc2, 0, 0, 0);
        acc2 = __builtin_amdgcn_mfma_f32_16x16x32_bf16(a21, bf1, acc2, 0, 0, 0);
        acc2 = __builtin_amdgcn_mfma_f32_16x16x32_bf16(a22, bf2, acc2, 0, 0, 0);
        const int sb = 32 + kq * 4;
        if (sb + 0 < cnt) out[(size_t)pv2.x * NOUT + n] = acc2[0] + H3;
        if (sb + 1 < cnt) out[(size_t)pv2.y * NOUT + n] = acc2[1] + H3;
        if (sb + 2 < cnt) out[(size_t)pv2.z * NOUT + n] = acc2[2] + H3;
        if (sb + 3 < cnt) out[(size_t)pv2.w * NOUT + n] = acc2[3] + H3;
    }
}

// ---------------------------------------------------------------------------
// Softmax: in-place row softmax * size_factor; blocks 0..15 also write
// inverse_dispersion = exp(px_r).
// ---------------------------------------------------------------------------
__global__ __launch_bounds__(256) void k_softmax(
    float*       __restrict__ out,
    const float* __restrict__ sf,
    const float* __restrict__ px_r)
{
    const int c   = blockIdx.x;
    const int tid = threadIdx.x;
    float4* row4 = reinterpret_cast<float4*>(out + (size_t)c * NOUT);

    float4 v[4];
    #pragma unroll
    for (int j = 0; j < 4; ++j) v[j] = row4[j * 256 + tid];

    float m = -3.4e38f;
    #pragma unroll
    for (int j = 0; j < 4; ++j)
        m = fmaxf(fmaxf(fmaxf(m, v[j].x), fmaxf(v[j].y, v[j].z)), v[j].w);

    #pragma unroll
    for (int off = 32; off > 0; off >>= 1)
        m = fmaxf(m, __shfl_xor(m, off, 64));

    __shared__ float s_red[8];
    const int wave = tid >> 6;
    const int lane = tid & 63;
    if (lane == 0) s_red[wave] = m;
    __syncthreads();
    m = fmaxf(fmaxf(s_red[0], s_red[1]), fmaxf(s_red[2], s_red[3]));

    float s = 0.f;
    #pragma unroll
    for (int j = 0; j < 4; ++j) {
        v[j].x = __expf(v[j].x - m); v[j].y = __expf(v[j].y - m);
        v[j].z = __expf(v[j].z - m); v[j].w = __expf(v[j].w - m);
        s += v[j].x + v[j].y + v[j].z + v[j].w;
    }
    #pragma unroll
    for (int off = 32; off > 0; off >>= 1)
        s += __shfl_xor(s, off, 64);
    if (lane == 0) s_red[4 + wave] = s;
    __syncthreads();
    s = s_red[4] + s_red[5] + s_red[6] + s_red[7];

    const float scale = sf[c] / s;
    #pragma unroll
    for (int j = 0; j < 4; ++j) {
        v[j].x *= scale; v[j].y *= scale; v[j].z *= scale; v[j].w *= scale;
        row4[j * 256 + tid] = v[j];
    }

    if (c < NOUT / 256) {                 // 16 blocks cover px_r
        const int i = c * 256 + tid;
        out[(size_t)B_SZ * NOUT + i] = __expf(px_r[i]);
    }
}

// ---------------------------------------------------------------------------
extern "C" void kernel_launch(void* const* d_in, const int* in_sizes, int n_in,
                              void* d_out, int out_size, void* d_ws, size_t ws_size,
                              hipStream_t stream)
{
    const float* z       = (const float*)d_in[0];
    const int*   idx     = (const int*)  d_in[1];
    const float* sf      = (const float*)d_in[2];
    const float* cont    = (const float*)d_in[3];
    const float* amat_W  = (const float*)d_in[4];
    const float* embed_A = (const float*)d_in[5];
    const float* eh3     = (const float*)d_in[6];
    const float* cont_W  = (const float*)d_in[7];
    const float* px_r    = (const float*)d_in[8];
    float* out = (float*)d_out;

    // ws layout (bytes): cnt[64] @0 | perm[64*48] @256 | Xt bf16 @16384
    //                    | Wt f32 @212992 | total ~1.75 MB
    char* ws = (char*)d_ws;
    int*            cnt_ws  = (int*)ws;
    int*            perm_ws = (int*)(ws + 256);
    unsigned short* Xt      = (unsigned short*)(ws + 16384);
    float*          Wt      = (float*)(ws + 212992);

    k_prep<<<WT_BLOCKS + XT_BLOCKS + 1, 256, 0, stream>>>(
        z, idx, cont, amat_W, cont_W, cnt_ws, perm_ws, Xt, Wt);

    dim3 grid1(NOUT / 16, NBATCH);        // 16384 single-wave blocks
    k_mfma<<<grid1, 64, 0, stream>>>(embed_A, eh3, Xt, Wt,
                                     cnt_ws, perm_ws, out);

    k_softmax<<<B_SZ, 256, 0, stream>>>(out, sf, px_r);
}

// Round 13
// 36.874 us; speedup vs baseline: 1.2874x; 1.2562x over previous
//
#include <hip/hip_runtime.h>
#include <hip/hip_bf16.h>

#define B_SZ   1024
#define NIN    64
#define NOUT   4096
#define NBATCH 64
#define NCONT  16
#define KTOT   96      // z(64) | cont(16) | zero-pad(16)
#define PCAP   48      // per-batch sample capacity (Poisson(16) max ~32)

#define WTB_UNITS  (256 * 3 * 64)             // 49152 16B-units
#define XT_ELEMS   (B_SZ * KTOT)              // 98304
#define WTB_BLOCKS (WTB_UNITS / 256)          // 192
#define XT_BLOCKS  (XT_ELEMS / 256)           // 384

typedef __attribute__((ext_vector_type(8))) short short8;   // 8 bf16 = 4 VGPR
typedef __attribute__((ext_vector_type(4))) float f32x4;

// f32 -> bf16 bits, round-to-nearest-even
__device__ __forceinline__ short f2bf(float f) {
    unsigned u = __float_as_uint(f);
    return (short)((u + 0x7FFFu + ((u >> 16) & 1u)) >> 16);
}
// pack 8 f32 (two float4) -> short8 bf16 in order
__device__ __forceinline__ short8 pk8(float4 a, float4 b) {
    short8 r;
    r[0]=f2bf(a.x); r[1]=f2bf(a.y); r[2]=f2bf(a.z); r[3]=f2bf(a.w);
    r[4]=f2bf(b.x); r[5]=f2bf(b.y); r[6]=f2bf(b.z); r[7]=f2bf(b.w);
    return r;
}
// K-permutation (applied to BOTH operands -> GEMM invariant):
// logical frag slot (kq, j) holds physical k = pi(kq,j) within each 32-block.
__device__ __forceinline__ int kpi(int kq, int j) {
    return (j < 4) ? (kq * 4 + j) : (16 + kq * 4 + (j - 4));
}

// ---------------------------------------------------------------------------
// Prep:
//  blocks [0,192):     Wtb frag-ordered bf16: unit u=(nt*3+ks)*64+lane holds
//                      8 bf16 of W[k=ks*32+pi(kq,j)][n=nt*16+nl]
//                      (W = [amat_W; cont_W; 0], K-concat scheme)
//  blocks [192,576):   Xt[c][k] = [z | cont | 0] bf16 (k-contig)
//  block  576:         perm/cnt (pad slots pre-zeroed)
// ---------------------------------------------------------------------------
__global__ __launch_bounds__(256) void k_prep(
    const float* __restrict__ z, const int* __restrict__ idx,
    const float* __restrict__ cont, const float* __restrict__ amat_W,
    const float* __restrict__ cont_W,
    int* __restrict__ cnt_ws, int* __restrict__ perm_ws,
    unsigned short* __restrict__ Xt, unsigned short* __restrict__ Wtb)
{
    const int bid = blockIdx.x, tid = threadIdx.x;

    if (bid < WTB_BLOCKS) {
        const int u   = bid * 256 + tid;
        const int nt  = u / 192, rem = u - nt * 192;
        const int ks  = rem >> 6, lane = rem & 63;
        const int kq  = lane >> 4, nl = lane & 15;
        const int n   = nt * 16 + nl;
        unsigned short v8[8];
        #pragma unroll
        for (int j = 0; j < 8; ++j) {
            const int k = ks * 32 + kpi(kq, j);
            float v = 0.f;
            if (k < NIN)              v = amat_W[k * NOUT + n];
            else if (k < NIN + NCONT) v = cont_W[(k - NIN) * NOUT + n];
            v8[j] = (unsigned short)f2bf(v);
        }
        *(int4*)(Wtb + (size_t)u * 8) = *(int4*)v8;       // 16B coalesced
    } else if (bid < WTB_BLOCKS + XT_BLOCKS) {
        const int i = (bid - WTB_BLOCKS) * 256 + tid;
        const int c = i / KTOT, k = i - c * KTOT;
        float v = 0.f;
        if (k < NIN)              v = z[c * NIN + k];
        else if (k < NIN + NCONT) v = cont[c * NCONT + (k - NIN)];
        Xt[i] = (unsigned short)f2bf(v);
    } else {                                  // perm / cnt (one block)
        __shared__ int lcnt[NBATCH];
        if (tid < NBATCH) lcnt[tid] = 0;
        for (int i = tid; i < NBATCH * PCAP; i += 256) perm_ws[i] = 0;
        __syncthreads();
        for (int c = tid; c < B_SZ; c += 256) {
            const int b = idx[c];
            const int p = atomicAdd(&lcnt[b], 1);
            if (p < PCAP) perm_ws[b * PCAP + p] = c;
        }
        __syncthreads();
        if (tid < NBATCH) cnt_ws[tid] = min(lcnt[tid], PCAP);
    }
}

// ---------------------------------------------------------------------------
// Xa: A-fragments pre-gathered per (batch, m-tile, ks), pi-permuted.
// unit u=(b*3+mt)*3+ks; elem [u*512 + lane*8 + j] = Xt[pb[mt*16+(lane&15)]]
//                                                     [ks*32 + pi(lane>>4, j)]
// 576 units x 64 lanes = 144 blocks x 256.  (needs perm -> after k_prep)
// ---------------------------------------------------------------------------
__global__ __launch_bounds__(256) void k_xa(
    const unsigned short* __restrict__ Xt, const int* __restrict__ perm_ws,
    unsigned short* __restrict__ Xa)
{
    const int t = blockIdx.x * 256 + threadIdx.x;
    const int u = t >> 6, lane = t & 63;
    const int b = u / 9, r = u - b * 9;
    const int mt = r / 3, ks = r - mt * 3;
    const int kq = lane >> 4, ml = lane & 15;
    const int c = perm_ws[b * PCAP + mt * 16 + ml];
    // pi: j<4 -> ks*32+kq*4+j (4 contig) ; j>=4 -> ks*32+16+kq*4+(j-4) (4 contig)
    const unsigned short* s0 = Xt + c * KTOT + ks * 32 + kq * 4;
    ushort4 lo = *(const ushort4*)s0;
    ushort4 hi = *(const ushort4*)(s0 + 16);
    unsigned short v8[8] = {lo.x, lo.y, lo.z, lo.w, hi.x, hi.y, hi.z, hi.w};
    *(int4*)(Xa + (size_t)u * 512 + lane * 8) = *(int4*)v8;
}

// ---------------------------------------------------------------------------
// Main GEMM. R12 proved the compiler innocent: asm-forced back-to-back loads
// still 1.36 TB/s -> the REQUESTS were the problem (16B chunks from 256B-
// strided rows = 32 half-used lines per instr). This version: K-permutation
// pi makes every embed load FULL-LINE (row + kq*16 -> 4 kq-lanes = 64B
// contiguous per row); A/W frags pre-gathered pi-consistently in prep ->
// contiguous 1KB per instr. W folded in via K-concat (h=[z|z|cont]x[A;Wz;Wc],
// 5 MFMA/tile) -> B-frags straight from memory, no VALU add.
// Frag layouts: A lane&15=m ; B lane&15=n ; C col=lane&15, row=kq*4+r
// [m89-verified, R6-R12-validated].
// ---------------------------------------------------------------------------
__global__ __launch_bounds__(64) void k_gemm(
    const float* __restrict__ embed_A,
    const float* __restrict__ embed_h3,
    const unsigned short* __restrict__ Xa,
    const unsigned short* __restrict__ Wtb,
    const int* __restrict__ cnt_ws,
    const int* __restrict__ perm_ws,
    float* __restrict__ out)
{
    const int lane = threadIdx.x;
    const int nl = lane & 15, kq = lane >> 4;
    const int nt = blockIdx.x;                    // 0..255
    const int b  = blockIdx.y;                    // 0..63
    const int n  = nt * 16 + nl;
    const int cnt = cnt_ws[b];                    // wave-uniform
    if (cnt == 0) return;
    const int ntiles = (cnt + 15) >> 4;

    const unsigned oxa  = (unsigned)(b * 9216 + lane * 16);        // mt0 base
    const unsigned oxa2 = oxa + 3072;                              // mt1 base
    const unsigned owt  = (unsigned)(nt * 3072 + lane * 16);
    const unsigned oe   = (unsigned)(((unsigned)(b * NOUT + n)) * 256 + kq * 16);
    const unsigned opv  = (unsigned)(b * (PCAP * 4) + kq * 16);
    const unsigned oh   = (unsigned)((b * NOUT + n) * 4);

    int4 AZ00, AZ01, AZ02, AZ10, AZ11, AZ12, WT0, WT1, WT2;
    int4 E00, E01, E10, E11, PV0, PV1;
    float H3;
    asm volatile(
        "global_load_dwordx4 %[e00], %[oe], %[ea]\n\t"
        "global_load_dwordx4 %[e01], %[oe], %[ea] offset:64\n\t"
        "global_load_dwordx4 %[e10], %[oe], %[ea] offset:128\n\t"
        "global_load_dwordx4 %[e11], %[oe], %[ea] offset:192\n\t"
        "global_load_dwordx4 %[a00], %[oxa], %[xa]\n\t"
        "global_load_dwordx4 %[a01], %[oxa], %[xa] offset:1024\n\t"
        "global_load_dwordx4 %[a02], %[oxa], %[xa] offset:2048\n\t"
        "global_load_dwordx4 %[a10], %[oxa2], %[xa]\n\t"
        "global_load_dwordx4 %[a11], %[oxa2], %[xa] offset:1024\n\t"
        "global_load_dwordx4 %[a12], %[oxa2], %[xa] offset:2048\n\t"
        "global_load_dwordx4 %[w0], %[owt], %[wb]\n\t"
        "global_load_dwordx4 %[w1], %[owt], %[wb] offset:1024\n\t"
        "global_load_dwordx4 %[w2], %[owt], %[wb] offset:2048\n\t"
        "global_load_dwordx4 %[pv0], %[opv], %[pm]\n\t"
        "global_load_dwordx4 %[pv1], %[opv], %[pm] offset:64\n\t"
        "global_load_dword   %[h3],  %[oh],  %[hp]\n\t"
        "s_waitcnt vmcnt(0)"
        : [e00]"=&v"(E00), [e01]"=&v"(E01), [e10]"=&v"(E10), [e11]"=&v"(E11),
          [a00]"=&v"(AZ00), [a01]"=&v"(AZ01), [a02]"=&v"(AZ02),
          [a10]"=&v"(AZ10), [a11]"=&v"(AZ11), [a12]"=&v"(AZ12),
          [w0]"=&v"(WT0), [w1]"=&v"(WT1), [w2]"=&v"(WT2),
          [pv0]"=&v"(PV0), [pv1]"=&v"(PV1), [h3]"=&v"(H3)
        : [oxa]"v"(oxa), [oxa2]"v"(oxa2), [owt]"v"(owt), [oe]"v"(oe),
          [opv]"v"(opv), [oh]"v"(oh),
          [ea]"s"(embed_A), [xa]"s"(Xa), [wb]"s"(Wtb),
          [pm]"s"(perm_ws), [hp]"s"(embed_h3)
        : "memory");
    __builtin_amdgcn_sched_barrier(0);

    // B-frags: embed (cvt f32->bf16, pi already satisfied by load layout) + W
    const short8 eb0 = pk8(*(const float4*)&E00, *(const float4*)&E01);
    const short8 eb1 = pk8(*(const float4*)&E10, *(const float4*)&E11);
    const short8 wt0 = *(const short8*)&WT0;
    const short8 wt1 = *(const short8*)&WT1;
    const short8 wt2 = *(const short8*)&WT2;

    {   // m-tile 0
        const short8 az0 = *(const short8*)&AZ00;
        const short8 az1 = *(const short8*)&AZ01;
        const short8 ac2 = *(const short8*)&AZ02;
        f32x4 acc = {0, 0, 0, 0};
        acc = __builtin_amdgcn_mfma_f32_16x16x32_bf16(az0, eb0, acc, 0, 0, 0);
        acc = __builtin_amdgcn_mfma_f32_16x16x32_bf16(az1, eb1, acc, 0, 0, 0);
        acc = __builtin_amdgcn_mfma_f32_16x16x32_bf16(az0, wt0, acc, 0, 0, 0);
        acc = __builtin_amdgcn_mfma_f32_16x16x32_bf16(az1, wt1, acc, 0, 0, 0);
        acc = __builtin_amdgcn_mfma_f32_16x16x32_bf16(ac2, wt2, acc, 0, 0, 0);
        const int sb = kq * 4;
        if (sb + 0 < cnt) out[(size_t)PV0.x * NOUT + n] = acc[0] + H3;
        if (sb + 1 < cnt) out[(size_t)PV0.y * NOUT + n] = acc[1] + H3;
        if (sb + 2 < cnt) out[(size_t)PV0.z * NOUT + n] = acc[2] + H3;
        if (sb + 3 < cnt) out[(size_t)PV0.w * NOUT + n] = acc[3] + H3;
    }
    if (ntiles > 1) {                             // m-tile 1 (uniform branch)
        const short8 az0 = *(const short8*)&AZ10;
        const short8 az1 = *(const short8*)&AZ11;
        const short8 ac2 = *(const short8*)&AZ12;
        f32x4 acc = {0, 0, 0, 0};
        acc = __builtin_amdgcn_mfma_f32_16x16x32_bf16(az0, eb0, acc, 0, 0, 0);
        acc = __builtin_amdgcn_mfma_f32_16x16x32_bf16(az1, eb1, acc, 0, 0, 0);
        acc = __builtin_amdgcn_mfma_f32_16x16x32_bf16(az0, wt0, acc, 0, 0, 0);
        acc = __builtin_amdgcn_mfma_f32_16x16x32_bf16(az1, wt1, acc, 0, 0, 0);
        acc = __builtin_amdgcn_mfma_f32_16x16x32_bf16(ac2, wt2, acc, 0, 0, 0);
        const int sb = 16 + kq * 4;
        if (sb + 0 < cnt) out[(size_t)PV1.x * NOUT + n] = acc[0] + H3;
        if (sb + 1 < cnt) out[(size_t)PV1.y * NOUT + n] = acc[1] + H3;
        if (sb + 2 < cnt) out[(size_t)PV1.z * NOUT + n] = acc[2] + H3;
        if (sb + 3 < cnt) out[(size_t)PV1.w * NOUT + n] = acc[3] + H3;
    }
    if (ntiles > 2) {                             // rare (cnt>32): plain path
        const unsigned short* xa2 = Xa + ((size_t)(b * 9 + 6)) * 512 + lane * 8;
        const short8 az0 = *(const short8*)(xa2);
        const short8 az1 = *(const short8*)(xa2 + 512);
        const short8 ac2 = *(const short8*)(xa2 + 1024);
        const int4 pv2 = *(const int4*)(perm_ws + b * PCAP + 32 + kq * 4);
        f32x4 acc = {0, 0, 0, 0};
        acc = __builtin_amdgcn_mfma_f32_16x16x32_bf16(az0, eb0, acc, 0, 0, 0);
        acc = __builtin_amdgcn_mfma_f32_16x16x32_bf16(az1, eb1, acc, 0, 0, 0);
        acc = __builtin_amdgcn_mfma_f32_16x16x32_bf16(az0, wt0, acc, 0, 0, 0);
        acc = __builtin_amdgcn_mfma_f32_16x16x32_bf16(az1, wt1, acc, 0, 0, 0);
        acc = __builtin_amdgcn_mfma_f32_16x16x32_bf16(ac2, wt2, acc, 0, 0, 0);
        const int sb = 32 + kq * 4;
        if (sb + 0 < cnt) out[(size_t)pv2.x * NOUT + n] = acc[0] + H3;
        if (sb + 1 < cnt) out[(size_t)pv2.y * NOUT + n] = acc[1] + H3;
        if (sb + 2 < cnt) out[(size_t)pv2.z * NOUT + n] = acc[2] + H3;
        if (sb + 3 < cnt) out[(size_t)pv2.w * NOUT + n] = acc[3] + H3;
    }
}

// ---------------------------------------------------------------------------
// Softmax: in-place row softmax * size_factor; blocks 0..15 also write
// inverse_dispersion = exp(px_r).
// ---------------------------------------------------------------------------
__global__ __launch_bounds__(256) void k_softmax(
    float*       __restrict__ out,
    const float* __restrict__ sf,
    const float* __restrict__ px_r)
{
    const int c   = blockIdx.x;
    const int tid = threadIdx.x;
    float4* row4 = reinterpret_cast<float4*>(out + (size_t)c * NOUT);

    float4 v[4];
    #pragma unroll
    for (int j = 0; j < 4; ++j) v[j] = row4[j * 256 + tid];

    float m = -3.4e38f;
    #pragma unroll
    for (int j = 0; j < 4; ++j)
        m = fmaxf(fmaxf(fmaxf(m, v[j].x), fmaxf(v[j].y, v[j].z)), v[j].w);

    #pragma unroll
    for (int off = 32; off > 0; off >>= 1)
        m = fmaxf(m, __shfl_xor(m, off, 64));

    __shared__ float s_red[8];
    const int wave = tid >> 6;
    const int lane = tid & 63;
    if (lane == 0) s_red[wave] = m;
    __syncthreads();
    m = fmaxf(fmaxf(s_red[0], s_red[1]), fmaxf(s_red[2], s_red[3]));

    float s = 0.f;
    #pragma unroll
    for (int j = 0; j < 4; ++j) {
        v[j].x = __expf(v[j].x - m); v[j].y = __expf(v[j].y - m);
        v[j].z = __expf(v[j].z - m); v[j].w = __expf(v[j].w - m);
        s += v[j].x + v[j].y + v[j].z + v[j].w;
    }
    #pragma unroll
    for (int off = 32; off > 0; off >>= 1)
        s += __shfl_xor(s, off, 64);
    if (lane == 0) s_red[4 + wave] = s;
    __syncthreads();
    s = s_red[4] + s_red[5] + s_red[6] + s_red[7];

    const float scale = sf[c] / s;
    #pragma unroll
    for (int j = 0; j < 4; ++j) {
        v[j].x *= scale; v[j].y *= scale; v[j].z *= scale; v[j].w *= scale;
        row4[j * 256 + tid] = v[j];
    }

    if (c < NOUT / 256) {                 // 16 blocks cover px_r
        const int i = c * 256 + tid;
        out[(size_t)B_SZ * NOUT + i] = __expf(px_r[i]);
    }
}

// ---------------------------------------------------------------------------
extern "C" void kernel_launch(void* const* d_in, const int* in_sizes, int n_in,
                              void* d_out, int out_size, void* d_ws, size_t ws_size,
                              hipStream_t stream)
{
    const float* z       = (const float*)d_in[0];
    const int*   idx     = (const int*)  d_in[1];
    const float* sf      = (const float*)d_in[2];
    const float* cont    = (const float*)d_in[3];
    const float* amat_W  = (const float*)d_in[4];
    const float* embed_A = (const float*)d_in[5];
    const float* eh3     = (const float*)d_in[6];
    const float* cont_W  = (const float*)d_in[7];
    const float* px_r    = (const float*)d_in[8];
    float* out = (float*)d_out;

    // ws (bytes): cnt[64]@0 | perm[64*48]@256 | Xt bf16 @16384 (196608)
    //             | Wtb bf16 @212992 (786432) | Xa bf16 @999424 (589824)
    //             total ~1.6 MB
    char* ws = (char*)d_ws;
    int*            cnt_ws  = (int*)ws;
    int*            perm_ws = (int*)(ws + 256);
    unsigned short* Xt      = (unsigned short*)(ws + 16384);
    unsigned short* Wtb     = (unsigned short*)(ws + 212992);
    unsigned short* Xa      = (unsigned short*)(ws + 999424);

    k_prep<<<WTB_BLOCKS + XT_BLOCKS + 1, 256, 0, stream>>>(
        z, idx, cont, amat_W, cont_W, cnt_ws, perm_ws, Xt, Wtb);

    k_xa<<<144, 256, 0, stream>>>(Xt, perm_ws, Xa);

    dim3 grid1(NOUT / 16, NBATCH);        // 16384 single-wave blocks
    k_gemm<<<grid1, 64, 0, stream>>>(embed_A, eh3, Xa, Wtb,
                                     cnt_ws, perm_ws, out);

    k_softmax<<<B_SZ, 256, 0, stream>>>(out, sf, px_r);
}